// Round 6
// baseline (449.066 us; speedup 1.0000x reference)
//
#include <hip/hip_runtime.h>

// Problem constants (fixed by reference)
#define CCH   128      // channels
#define NF    512      // node_feats row = C + 3C
#define OUTF  1408     // 2C + 3*3C
#define RDIM  8

#define INV_SQRT8  0.35355339059327373f
#define INV_SQRT10 0.31622776601683794f
#define SQRT3      1.7320508075688772f

typedef _Float16 half2_t __attribute__((ext_vector_type(2)));
typedef _Float16 f16x8  __attribute__((ext_vector_type(8)));
typedef float    f32x4  __attribute__((ext_vector_type(4)));

__device__ __forceinline__ float silu(float x) {
    return x / (1.0f + __expf(-x));
}

__device__ __forceinline__ unsigned int packh2(float lo, float hi) {
    half2_t h = { (_Float16)lo, (_Float16)hi };
    return __builtin_bit_cast(unsigned int, h);
}
__device__ __forceinline__ float h2lo(unsigned int u) {
    return (float)__builtin_bit_cast(half2_t, u).x;
}
__device__ __forceinline__ float h2hi(unsigned int u) {
    return (float)__builtin_bit_cast(half2_t, u).y;
}

// (h.x*w.x + h.y*w.y + c) via v_dot2_f32_f16
__device__ __forceinline__ float dot2(unsigned int h, unsigned int w, float c) {
#if __has_builtin(__builtin_amdgcn_fdot2)
    return __builtin_amdgcn_fdot2(__builtin_bit_cast(half2_t, h),
                                  __builtin_bit_cast(half2_t, w), c, false);
#else
    half2_t a = __builtin_bit_cast(half2_t, h);
    half2_t b = __builtin_bit_cast(half2_t, w);
    return c + (float)a.x * (float)b.x + (float)a.y * (float)b.y;
#endif
}

// ---------------- CSR build ----------------
__global__ void k_zero(int* __restrict__ p, int n) {
    int i = blockIdx.x * 256 + threadIdx.x;
    if (i < n) p[i] = 0;
}

__global__ void k_hist(const int* __restrict__ recv, int* __restrict__ counts, int E) {
    int i = blockIdx.x * 256 + threadIdx.x;
    if (i < E) atomicAdd(&counts[recv[i]], 1);
}

__global__ void k_scan(const int* __restrict__ counts, int* __restrict__ offsets,
                       int* __restrict__ cursor, int n) {
    __shared__ int wsum[16];
    int t = threadIdx.x;
    int lane = t & 63, wid = t >> 6;
    int carry = 0;
    for (int base = 0; base < n; base += 1024) {
        int i = base + t;
        int x = (i < n) ? counts[i] : 0;
        int s = x;
        #pragma unroll
        for (int off = 1; off < 64; off <<= 1) {
            int v = __shfl_up(s, off, 64);
            if (lane >= off) s += v;
        }
        if (lane == 63) wsum[wid] = s;
        __syncthreads();
        if (wid == 0) {
            int v = (lane < 16) ? wsum[lane] : 0;
            #pragma unroll
            for (int off = 1; off < 16; off <<= 1) {
                int u = __shfl_up(v, off, 64);
                if (lane >= off) v += u;
            }
            if (lane < 16) wsum[lane] = v;
        }
        __syncthreads();
        int excl_wave = (wid > 0) ? wsum[wid - 1] : 0;
        int incl = s + excl_wave;
        if (i < n) {
            int ex = carry + incl - x;
            offsets[i] = ex;
            cursor[i]  = ex;
        }
        carry += wsum[15];
        __syncthreads();
    }
    if (t == 0) offsets[n] = carry;
}

__global__ void k_perm(const int* __restrict__ recv, int* __restrict__ cursor,
                       int* __restrict__ perm, int E) {
    int i = blockIdx.x * 256 + threadIdx.x;
    if (i < E) {
        int p = atomicAdd(&cursor[recv[i]], 1);
        perm[p] = i;
    }
}

// ---------------- cooperative radial MLP ----------------
// Wave handles 4 edges per iteration; lane owns hidden unit j.
// hs is written as _Float16 and read via casted uint* -> REQUIRES __syncthreads()
// fences (round-5 NaN: without barriers, TBAA let the compiler hoist packed
// reads above the LDS writes). Loop iterates on block-uniform base so barrier
// control flow stays uniform; out-of-range waves run clamped work, store off.
__global__ __launch_bounds__(256, 4) void k_mlp2(
    const float* __restrict__ radial,
    const float* __restrict__ w0, const float* __restrict__ w1,
    const float* __restrict__ w2, _Float16* __restrict__ h2out, int E)
{
    __shared__ float        w0s[8 * 64];     // 2 KB
    __shared__ unsigned int w1p[32 * 64];    // 8 KB
    __shared__ unsigned int w2p[32 * 64];    // 8 KB
    __shared__ _Float16     hs[4][4][64];    // [wave][edge][unit] 2 KB

    for (int idx = threadIdx.x; idx < 512; idx += 256) w0s[idx] = w0[idx];
    for (int idx = threadIdx.x; idx < 2048; idx += 256) {
        int j = idx & 63, kp = idx >> 6;
        w1p[idx] = packh2(w1[(2 * kp) * 64 + j], w1[(2 * kp + 1) * 64 + j]);
        w2p[idx] = packh2(w2[(2 * kp) * 64 + j], w2[(2 * kp + 1) * 64 + j]);
    }
    __syncthreads();

    const int lane = threadIdx.x & 63;
    const int wid  = threadIdx.x >> 6;
    unsigned int* hsu = (unsigned int*)&hs[wid][0][0];   // [q*32 + kp]

    float w0r[8];
    #pragma unroll
    for (int k = 0; k < 8; k++) w0r[k] = w0s[k * 64 + lane];

    int nquads = (E + 3) >> 2;
    for (int base = blockIdx.x * 4; base < nquads; base += gridDim.x * 4) {
        int qd = base + wid;                       // may exceed nquads
        bool active = qd < nquads;
        int e0 = (active ? qd : nquads - 1) * 4;

        // L0
        #pragma unroll
        for (int q = 0; q < 4; q++) {
            int e = e0 + q; if (e >= E) e = E - 1;
            const float* r = radial + (size_t)e * RDIM;
            float acc = 0.f;
            #pragma unroll
            for (int k = 0; k < 8; k++) acc += r[k] * w0r[k];
            hs[wid][q][lane] = (_Float16)silu(acc * INV_SQRT8);
        }
        __syncthreads();

        // L1
        float acc1[4] = {0.f, 0.f, 0.f, 0.f};
        #pragma unroll 4
        for (int kp = 0; kp < 32; kp++) {
            unsigned int w = w1p[kp * 64 + lane];
            #pragma unroll
            for (int q = 0; q < 4; q++) acc1[q] = dot2(hsu[q * 32 + kp], w, acc1[q]);
        }
        __syncthreads();
        #pragma unroll
        for (int q = 0; q < 4; q++) hs[wid][q][lane] = (_Float16)silu(acc1[q] * 0.125f);
        __syncthreads();

        // L2
        float acc2[4] = {0.f, 0.f, 0.f, 0.f};
        #pragma unroll 4
        for (int kp = 0; kp < 32; kp++) {
            unsigned int w = w2p[kp * 64 + lane];
            #pragma unroll
            for (int q = 0; q < 4; q++) acc2[q] = dot2(hsu[q * 32 + kp], w, acc2[q]);
        }
        if (active) {
            #pragma unroll
            for (int q = 0; q < 4; q++) {
                int e = e0 + q;
                if (e < E) h2out[(size_t)e * 64 + lane] = (_Float16)silu(acc2[q] * 0.125f);
            }
        }
        __syncthreads();   // fence L2 reads vs next iteration's L0 writes
    }
}

// ---------------- MFMA mix GEMM: mix[E x 640] = h2[E x 64] @ w3[64 x 640] ----------------
// Wave per 16-edge group (grid-stride). A from h2 (coalesced 16B loads,
// A[m=lane&15][k=quad*8+j]). B from LDS w3^T (f16, [n][k] rows of 32 dwords,
// 16B-chunk XOR swizzle -> 2-way banks = free). C/D: col=lane&15, row=quad*4+reg.
// Cols c and c+64 share lane&15 -> pack (c,c+64) f16 pairs directly.
// LDS = 80 KB -> 2 blocks(512 thr)/CU.
__global__ __launch_bounds__(512, 4) void k_mixm(
    const float* __restrict__ w3,
    const unsigned int* __restrict__ h2u,    // h2 rows: 32 dwords (64 f16)
    unsigned int* __restrict__ mixp, int E)
{
    __shared__ unsigned int ws3[640 * 32];   // 81920 B

    for (int idx = threadIdx.x; idx < 640 * 32; idx += 512) {
        int n = idx >> 5, dw = idx & 31;
        int q = dw >> 2, j = dw & 3;
        int kb = q * 8 + 2 * j;
        unsigned int val = packh2(w3[kb * 640 + n], w3[(kb + 1) * 640 + n]);
        ws3[(n << 5) + (((q ^ (n & 7)) << 2) + j)] = val;
    }
    __syncthreads();

    const int lane = threadIdx.x & 63;
    const int quad = lane >> 4, nl = lane & 15;
    const float sc = 0.125f * INV_SQRT10;
    int ngroups = (E + 15) >> 4;

    for (int g = blockIdx.x * 8 + (threadIdx.x >> 6); g < ngroups; g += gridDim.x * 8) {
        int eb = g << 4;
        int erow = eb + nl; if (erow >= E) erow = E - 1;
        const uint4* ha = (const uint4*)(h2u + (size_t)erow * 32);
        f16x8 a0 = __builtin_bit_cast(f16x8, ha[quad]);        // k = quad*8 .. +7
        f16x8 a1 = __builtin_bit_cast(f16x8, ha[quad + 4]);    // k = 32 + quad*8 .. +7

        #pragma unroll
        for (int mm = 0; mm < 5; mm++) {
            f32x4 acc[8];
            #pragma unroll
            for (int t = 0; t < 8; t++) acc[t] = (f32x4){0.f, 0.f, 0.f, 0.f};

            #pragma unroll
            for (int t = 0; t < 8; t++) {
                int nn = (mm * 8 + t) * 16 + nl;               // output column
                const unsigned int* bp = ws3 + (nn << 5);
                int sw = nn & 7;
                f16x8 b0 = __builtin_bit_cast(f16x8, *(const uint4*)(bp + ((quad ^ sw) << 2)));
                f16x8 b1 = __builtin_bit_cast(f16x8, *(const uint4*)(bp + (((quad + 4) ^ sw) << 2)));
                acc[t] = __builtin_amdgcn_mfma_f32_16x16x32_f16(a0, b0, acc[t], 0, 0, 0);
                acc[t] = __builtin_amdgcn_mfma_f32_16x16x32_f16(a1, b1, acc[t], 0, 0, 0);
            }

            float s = (mm == 4) ? sc * SQRT3 : sc;
            #pragma unroll
            for (int tp = 0; tp < 4; tp++) {
                #pragma unroll
                for (int r = 0; r < 4; r++) {
                    int e = eb + quad * 4 + r;
                    if (e < E) {
                        mixp[(size_t)e * 320 + mm * 64 + tp * 16 + nl] =
                            packh2(acc[tp][r] * s, acc[tp + 4][r] * s);
                    }
                }
            }
        }
    }
}

// ---------------- lean gather, 2-edge software pipeline ----------------
__global__ __launch_bounds__(256, 4) void k_gather(
    const float* __restrict__ vectors,
    const float* __restrict__ node_feats,
    const int*   __restrict__ senders,
    const int*   __restrict__ offsets,
    const int*   __restrict__ perm,
    const unsigned int* __restrict__ mixp,
    float* __restrict__ out, int N)
{
    const int lane = threadIdx.x & 63;
    int node = blockIdx.x * 4 + (threadIdx.x >> 6);
    if (node >= N) return;

    int beg = offsets[node];
    int end = offsets[node + 1];

    float aS[2]     = {0.f, 0.f};
    float aT0[2]    = {0.f, 0.f};
    float aV0[2][3] = {{0.f,0.f,0.f},{0.f,0.f,0.f}};
    float aV1[2][3] = {{0.f,0.f,0.f},{0.f,0.f,0.f}};
    float aV2[2][3] = {{0.f,0.f,0.f},{0.f,0.f,0.f}};

    for (int i = beg; i < end; i += 2) {
        int cnt = end - i; if (cnt > 2) cnt = 2;
        int ei[2];
        ei[0] = perm[i];
        ei[1] = (cnt == 2) ? perm[i + 1] : ei[0];

        float3 ve[2];
        const float* nfp[2];
        unsigned int u[2][5];
        #pragma unroll
        for (int q = 0; q < 2; q++) {
            int e = ei[q];
            ve[q] = *(const float3*)(vectors + (size_t)e * 3);
            nfp[q] = node_feats + (size_t)senders[e] * NF;
            const unsigned int* mp = mixp + (size_t)e * 320 + lane;
            #pragma unroll
            for (int m = 0; m < 5; m++) u[q][m] = mp[m * 64];
        }

        #pragma unroll
        for (int q = 0; q < 2; q++) {
            if (q < cnt) {
                float vx = ve[q].x, vy = ve[q].y, vz = ve[q].z;
                float inv = rsqrtf(vx * vx + vy * vy + vz * vz);
                float rx = vx * inv, ry = vy * inv, rz = vz * inv;
                const float* nf = nfp[q];
                #pragma unroll
                for (int t = 0; t < 2; t++) {
                    int c = lane + 64 * t;
                    float ssv = nf[c];
                    float3 vv = *(const float3*)(nf + CCH + 3 * c);
                    float v0 = vv.x, v1 = vv.y, v2 = vv.z;
                    float d = rx * v0 + ry * v1 + rz * v2;

                    float m0 = t ? h2hi(u[q][0]) : h2lo(u[q][0]);
                    float m1 = t ? h2hi(u[q][1]) : h2lo(u[q][1]);
                    float m2 = t ? h2hi(u[q][2]) : h2lo(u[q][2]);
                    float m3 = t ? h2hi(u[q][3]) : h2lo(u[q][3]);
                    float m4 = t ? h2hi(u[q][4]) : h2lo(u[q][4]);

                    aS[t]  += ssv * m0;
                    aT0[t] += d * m1;
                    aV0[t][0] += v0 * m2;
                    aV0[t][1] += v1 * m2;
                    aV0[t][2] += v2 * m2;
                    aV1[t][0] += ssv * rx * m3;
                    aV1[t][1] += ssv * ry * m3;
                    aV1[t][2] += ssv * rz * m3;
                    aV2[t][0] += (d * rx - v0 * (1.f / 3.f)) * m4;
                    aV2[t][1] += (d * ry - v1 * (1.f / 3.f)) * m4;
                    aV2[t][2] += (d * rz - v2 * (1.f / 3.f)) * m4;
                }
            }
        }
    }

    float* ob = out + (size_t)node * OUTF;
    #pragma unroll
    for (int t = 0; t < 2; t++) {
        int c = lane + 64 * t;
        ob[c]                = aS[t];
        ob[CCH + c]          = aT0[t];
        ob[256  + 3 * c + 0] = aV0[t][0];
        ob[256  + 3 * c + 1] = aV0[t][1];
        ob[256  + 3 * c + 2] = aV0[t][2];
        ob[640  + 3 * c + 0] = aV1[t][0];
        ob[640  + 3 * c + 1] = aV1[t][1];
        ob[640  + 3 * c + 2] = aV1[t][2];
        ob[1024 + 3 * c + 0] = aV2[t][0];
        ob[1024 + 3 * c + 1] = aV2[t][1];
        ob[1024 + 3 * c + 2] = aV2[t][2];
    }
}

// ---------------- fallback fused gather (small-ws path only) ----------------
__global__ __launch_bounds__(512, 4) void k_main_fused(
    const float* __restrict__ vectors,
    const float* __restrict__ node_feats,
    const float* __restrict__ w3,
    const int*   __restrict__ senders,
    const int*   __restrict__ offsets,
    const int*   __restrict__ perm,
    const unsigned int* __restrict__ h2g,
    int* __restrict__ ctr,
    float* __restrict__ out, int N)
{
    __shared__ uint4 wA[32 * 64];
    __shared__ uint4 wB[32 * 64];
    __shared__ uint2 wC[32 * 64];

    for (int idx = threadIdx.x; idx < 32 * 64; idx += 512) {
        int lane = idx & 63, kp = idx >> 6;
        const float* r0 = w3 + (2 * kp) * 640;
        const float* r1 = r0 + 640;
        uint4 A, B; uint2 Cc;
        A.x = packh2(r0[lane],       r1[lane]);
        A.y = packh2(r0[lane + 64],  r1[lane + 64]);
        A.z = packh2(r0[lane + 128], r1[lane + 128]);
        A.w = packh2(r0[lane + 192], r1[lane + 192]);
        B.x = packh2(r0[lane + 256], r1[lane + 256]);
        B.y = packh2(r0[lane + 320], r1[lane + 320]);
        B.z = packh2(r0[lane + 384], r1[lane + 384]);
        B.w = packh2(r0[lane + 448], r1[lane + 448]);
        Cc.x = packh2(r0[lane + 512], r1[lane + 512]);
        Cc.y = packh2(r0[lane + 576], r1[lane + 576]);
        wA[idx] = A; wB[idx] = B; wC[idx] = Cc;
    }
    __syncthreads();

    const int lane = threadIdx.x & 63;

    while (true) {
        int t0 = 0;
        if (lane == 0) t0 = atomicAdd(ctr, 1);
        int node = __shfl(t0, 0, 64);
        if (node >= N) break;
        node = __builtin_amdgcn_readfirstlane(node);

        int beg = offsets[node];
        int end = offsets[node + 1];

        float aS[2]     = {0.f, 0.f};
        float aT0[2]    = {0.f, 0.f};
        float aV0[2][3] = {{0.f,0.f,0.f},{0.f,0.f,0.f}};
        float aV1[2][3] = {{0.f,0.f,0.f},{0.f,0.f,0.f}};
        float aV2[2][3] = {{0.f,0.f,0.f},{0.f,0.f,0.f}};

        for (int i0 = beg; i0 < end; i0 += 4) {
            int rem = end - i0;
            int nq = rem < 4 ? rem : 4;

            const unsigned int* hrow[4];
            float rnx[4], rny[4], rnz[4];
            int   snd[4];

            #pragma unroll
            for (int q = 0; q < 4; q++) {
                int e = (q < nq) ? perm[i0 + q] : perm[i0];
                e = __builtin_amdgcn_readfirstlane(e);
                hrow[q] = h2g + (size_t)e * 32;
                if (q < nq) {
                    float vx = vectors[(size_t)e * 3 + 0];
                    float vy = vectors[(size_t)e * 3 + 1];
                    float vz = vectors[(size_t)e * 3 + 2];
                    float inv = rsqrtf(vx * vx + vy * vy + vz * vz);
                    rnx[q] = vx * inv; rny[q] = vy * inv; rnz[q] = vz * inv;
                    snd[q] = senders[e];
                }
            }

            float mixv[4][10];
            #pragma unroll
            for (int q = 0; q < 4; q++)
                #pragma unroll
                for (int m = 0; m < 10; m++) mixv[q][m] = 0.f;

            #pragma unroll 4
            for (int kp = 0; kp < 32; kp++) {
                unsigned int hq[4];
                #pragma unroll
                for (int q = 0; q < 4; q++) hq[q] = hrow[q][kp];
                uint4 A  = wA[kp * 64 + lane];
                uint4 B  = wB[kp * 64 + lane];
                uint2 Cc = wC[kp * 64 + lane];
                #pragma unroll
                for (int q = 0; q < 4; q++) {
                    unsigned int h = hq[q];
                    mixv[q][0] = dot2(h, A.x,  mixv[q][0]);
                    mixv[q][1] = dot2(h, A.y,  mixv[q][1]);
                    mixv[q][2] = dot2(h, A.z,  mixv[q][2]);
                    mixv[q][3] = dot2(h, A.w,  mixv[q][3]);
                    mixv[q][4] = dot2(h, B.x,  mixv[q][4]);
                    mixv[q][5] = dot2(h, B.y,  mixv[q][5]);
                    mixv[q][6] = dot2(h, B.z,  mixv[q][6]);
                    mixv[q][7] = dot2(h, B.w,  mixv[q][7]);
                    mixv[q][8] = dot2(h, Cc.x, mixv[q][8]);
                    mixv[q][9] = dot2(h, Cc.y, mixv[q][9]);
                }
            }

            const float sc = 0.125f * INV_SQRT10;
            #pragma unroll
            for (int q = 0; q < 4; q++) {
                if (q < nq) {
                    const float* nf = node_feats + (size_t)snd[q] * NF;
                    #pragma unroll
                    for (int t = 0; t < 2; t++) {
                        int c = lane + 64 * t;
                        float ssv = nf[c];
                        float v0 = nf[CCH + 3 * c + 0];
                        float v1 = nf[CCH + 3 * c + 1];
                        float v2 = nf[CCH + 3 * c + 2];
                        float d = rnx[q] * v0 + rny[q] * v1 + rnz[q] * v2;

                        float m0 = mixv[q][t]     * sc;
                        float m1 = mixv[q][2 + t] * sc;
                        float m2 = mixv[q][4 + t] * sc;
                        float m3 = mixv[q][6 + t] * sc;
                        float m4 = mixv[q][8 + t] * sc * SQRT3;

                        aS[t]  += ssv * m0;
                        aT0[t] += d * m1;
                        aV0[t][0] += v0 * m2;
                        aV0[t][1] += v1 * m2;
                        aV0[t][2] += v2 * m2;
                        aV1[t][0] += ssv * rnx[q] * m3;
                        aV1[t][1] += ssv * rny[q] * m3;
                        aV1[t][2] += ssv * rnz[q] * m3;
                        aV2[t][0] += (d * rnx[q] - v0 * (1.f / 3.f)) * m4;
                        aV2[t][1] += (d * rny[q] - v1 * (1.f / 3.f)) * m4;
                        aV2[t][2] += (d * rnz[q] - v2 * (1.f / 3.f)) * m4;
                    }
                }
            }
        }

        float* ob = out + (size_t)node * OUTF;
        #pragma unroll
        for (int t = 0; t < 2; t++) {
            int c = lane + 64 * t;
            ob[c]                = aS[t];
            ob[CCH + c]          = aT0[t];
            ob[256  + 3 * c + 0] = aV0[t][0];
            ob[256  + 3 * c + 1] = aV0[t][1];
            ob[256  + 3 * c + 2] = aV0[t][2];
            ob[640  + 3 * c + 0] = aV1[t][0];
            ob[640  + 3 * c + 1] = aV1[t][1];
            ob[640  + 3 * c + 2] = aV1[t][2];
            ob[1024 + 3 * c + 0] = aV2[t][0];
            ob[1024 + 3 * c + 1] = aV2[t][1];
            ob[1024 + 3 * c + 2] = aV2[t][2];
        }
    }
}

extern "C" void kernel_launch(void* const* d_in, const int* in_sizes, int n_in,
                              void* d_out, int out_size, void* d_ws, size_t ws_size,
                              hipStream_t stream) {
    const float* vectors    = (const float*)d_in[0];
    const float* node_feats = (const float*)d_in[1];
    const float* radial     = (const float*)d_in[2];
    const float* w0         = (const float*)d_in[3];
    const float* w1         = (const float*)d_in[4];
    const float* w2         = (const float*)d_in[5];
    const float* w3         = (const float*)d_in[6];
    const int*   senders    = (const int*)d_in[7];
    const int*   receivers  = (const int*)d_in[8];

    int E = in_sizes[0] / 3;
    int N = in_sizes[1] / NF;

    // ws layout (4-byte units): mixp[E*320] | h2[E*32] | counts[N] | ctr[1] |
    //                           offsets[N+1] | cursor[N] | perm[E]
    size_t small_elems = (size_t)E * 32 + N + 1 + (N + 1) + N + E;
    size_t full_elems  = (size_t)E * 320 + small_elems;
    bool big = ws_size >= full_elems * 4;

    unsigned int* mixp = (unsigned int*)d_ws;
    unsigned int* h2u  = mixp + (big ? (size_t)E * 320 : 0);
    int* counts  = (int*)(h2u + (size_t)E * 32);
    int* ctr     = counts + N;
    int* offsets = ctr + 1;
    int* cursor  = offsets + N + 1;
    int* perm    = cursor + N;
    _Float16* h2f = (_Float16*)h2u;

    k_zero<<<(N + 1 + 255) / 256, 256, 0, stream>>>(counts, N + 1);
    k_hist<<<(E + 255) / 256, 256, 0, stream>>>(receivers, counts, E);
    k_scan<<<1, 1024, 0, stream>>>(counts, offsets, cursor, N);
    k_perm<<<(E + 255) / 256, 256, 0, stream>>>(receivers, cursor, perm, E);
    k_mlp2<<<1024, 256, 0, stream>>>(radial, w0, w1, w2, h2f, E);

    if (big) {
        k_mixm<<<512, 512, 0, stream>>>(w3, h2u, mixp, E);
        k_gather<<<(N + 3) / 4, 256, 0, stream>>>(vectors, node_feats, senders,
                                                  offsets, perm, mixp,
                                                  (float*)d_out, N);
    } else {
        k_main_fused<<<512, 512, 0, stream>>>(vectors, node_feats, w3, senders,
                                              offsets, perm, h2u, ctr,
                                              (float*)d_out, N);
    }
}

// Round 7
// 277.858 us; speedup vs baseline: 1.6162x; 1.6162x over previous
//
#include <hip/hip_runtime.h>

// Problem constants (fixed by reference)
#define CCH   128      // channels
#define NF    512      // node_feats row = C + 3C
#define OUTF  1408     // 2C + 3*3C
#define RDIM  8

#define INV_SQRT8  0.35355339059327373f
#define INV_SQRT10 0.31622776601683794f
#define SQRT3      1.7320508075688772f

typedef _Float16 half2_t __attribute__((ext_vector_type(2)));
typedef _Float16 f16x8  __attribute__((ext_vector_type(8)));
typedef float    f32x4  __attribute__((ext_vector_type(4)));

__device__ __forceinline__ float silu(float x) {
    return x / (1.0f + __expf(-x));
}

__device__ __forceinline__ unsigned int packh2(float lo, float hi) {
    half2_t h = { (_Float16)lo, (_Float16)hi };
    return __builtin_bit_cast(unsigned int, h);
}
__device__ __forceinline__ float h2lo(unsigned int u) {
    return (float)__builtin_bit_cast(half2_t, u).x;
}
__device__ __forceinline__ float h2hi(unsigned int u) {
    return (float)__builtin_bit_cast(half2_t, u).y;
}

// (h.x*w.x + h.y*w.y + c) via v_dot2_f32_f16
__device__ __forceinline__ float dot2(unsigned int h, unsigned int w, float c) {
#if __has_builtin(__builtin_amdgcn_fdot2)
    return __builtin_amdgcn_fdot2(__builtin_bit_cast(half2_t, h),
                                  __builtin_bit_cast(half2_t, w), c, false);
#else
    half2_t a = __builtin_bit_cast(half2_t, h);
    half2_t b = __builtin_bit_cast(half2_t, w);
    return c + (float)a.x * (float)b.x + (float)a.y * (float)b.y;
#endif
}

// ---------------- CSR build ----------------
__global__ void k_zero(int* __restrict__ p, int n) {
    int i = blockIdx.x * 256 + threadIdx.x;
    if (i < n) p[i] = 0;
}

__global__ void k_hist(const int* __restrict__ recv, int* __restrict__ counts, int E) {
    int i = blockIdx.x * 256 + threadIdx.x;
    if (i < E) atomicAdd(&counts[recv[i]], 1);
}

__global__ void k_scan(const int* __restrict__ counts, int* __restrict__ offsets,
                       int* __restrict__ cursor, int n) {
    __shared__ int wsum[16];
    int t = threadIdx.x;
    int lane = t & 63, wid = t >> 6;
    int carry = 0;
    for (int base = 0; base < n; base += 1024) {
        int i = base + t;
        int x = (i < n) ? counts[i] : 0;
        int s = x;
        #pragma unroll
        for (int off = 1; off < 64; off <<= 1) {
            int v = __shfl_up(s, off, 64);
            if (lane >= off) s += v;
        }
        if (lane == 63) wsum[wid] = s;
        __syncthreads();
        if (wid == 0) {
            int v = (lane < 16) ? wsum[lane] : 0;
            #pragma unroll
            for (int off = 1; off < 16; off <<= 1) {
                int u = __shfl_up(v, off, 64);
                if (lane >= off) v += u;
            }
            if (lane < 16) wsum[lane] = v;
        }
        __syncthreads();
        int excl_wave = (wid > 0) ? wsum[wid - 1] : 0;
        int incl = s + excl_wave;
        if (i < n) {
            int ex = carry + incl - x;
            offsets[i] = ex;
            cursor[i]  = ex;
        }
        carry += wsum[15];
        __syncthreads();
    }
    if (t == 0) offsets[n] = carry;
}

// perm + edge->slot map + packed per-slot edge record {sender, vx, vy, vz}
__global__ void k_perm2(const int* __restrict__ recv, const int* __restrict__ send,
                        const float* __restrict__ vectors,
                        int* __restrict__ cursor, int* __restrict__ perm,
                        int* __restrict__ epos, float4* __restrict__ esrec, int E) {
    int i = blockIdx.x * 256 + threadIdx.x;
    if (i < E) {
        int p = atomicAdd(&cursor[recv[i]], 1);
        perm[p] = i;
        epos[i] = p;
        float3 v = *(const float3*)(vectors + (size_t)i * 3);
        esrec[p] = make_float4(__int_as_float(send[i]), v.x, v.y, v.z);
    }
}

// ---------------- cooperative radial MLP (round-6 verified) ----------------
__global__ __launch_bounds__(256, 4) void k_mlp2(
    const float* __restrict__ radial,
    const float* __restrict__ w0, const float* __restrict__ w1,
    const float* __restrict__ w2, _Float16* __restrict__ h2out, int E)
{
    __shared__ float        w0s[8 * 64];     // 2 KB
    __shared__ unsigned int w1p[32 * 64];    // 8 KB
    __shared__ unsigned int w2p[32 * 64];    // 8 KB
    __shared__ _Float16     hs[4][4][64];    // [wave][edge][unit] 2 KB

    for (int idx = threadIdx.x; idx < 512; idx += 256) w0s[idx] = w0[idx];
    for (int idx = threadIdx.x; idx < 2048; idx += 256) {
        int j = idx & 63, kp = idx >> 6;
        w1p[idx] = packh2(w1[(2 * kp) * 64 + j], w1[(2 * kp + 1) * 64 + j]);
        w2p[idx] = packh2(w2[(2 * kp) * 64 + j], w2[(2 * kp + 1) * 64 + j]);
    }
    __syncthreads();

    const int lane = threadIdx.x & 63;
    const int wid  = threadIdx.x >> 6;
    unsigned int* hsu = (unsigned int*)&hs[wid][0][0];   // [q*32 + kp]

    float w0r[8];
    #pragma unroll
    for (int k = 0; k < 8; k++) w0r[k] = w0s[k * 64 + lane];

    int nquads = (E + 3) >> 2;
    for (int base = blockIdx.x * 4; base < nquads; base += gridDim.x * 4) {
        int qd = base + wid;
        bool active = qd < nquads;
        int e0 = (active ? qd : nquads - 1) * 4;

        #pragma unroll
        for (int q = 0; q < 4; q++) {
            int e = e0 + q; if (e >= E) e = E - 1;
            const float* r = radial + (size_t)e * RDIM;
            float acc = 0.f;
            #pragma unroll
            for (int k = 0; k < 8; k++) acc += r[k] * w0r[k];
            hs[wid][q][lane] = (_Float16)silu(acc * INV_SQRT8);
        }
        __syncthreads();

        float acc1[4] = {0.f, 0.f, 0.f, 0.f};
        #pragma unroll 4
        for (int kp = 0; kp < 32; kp++) {
            unsigned int w = w1p[kp * 64 + lane];
            #pragma unroll
            for (int q = 0; q < 4; q++) acc1[q] = dot2(hsu[q * 32 + kp], w, acc1[q]);
        }
        __syncthreads();
        #pragma unroll
        for (int q = 0; q < 4; q++) hs[wid][q][lane] = (_Float16)silu(acc1[q] * 0.125f);
        __syncthreads();

        float acc2[4] = {0.f, 0.f, 0.f, 0.f};
        #pragma unroll 4
        for (int kp = 0; kp < 32; kp++) {
            unsigned int w = w2p[kp * 64 + lane];
            #pragma unroll
            for (int q = 0; q < 4; q++) acc2[q] = dot2(hsu[q * 32 + kp], w, acc2[q]);
        }
        if (active) {
            #pragma unroll
            for (int q = 0; q < 4; q++) {
                int e = e0 + q;
                if (e < E) h2out[(size_t)e * 64 + lane] = (_Float16)silu(acc2[q] * 0.125f);
            }
        }
        __syncthreads();
    }
}

// ---------------- MFMA mix GEMM with LDS-transposed, CSR-ordered epilogue ----
// mix[E x 640] = h2[E x 64] @ w3[64 x 640]; MFMA core verified in round 6.
// Round-6 regression: direct C-frag stores emit 4x scattered 64B segments ->
// partial-line RMW (FETCH 203MB, WRITE 385MB). Fix: per-wave LDS transpose
// (row stride 68 dwords -> 2-way banks = free), then one 256B fully-coalesced
// store per edge row, placed at CSR slot epos[e] so k_gather2 reads stream
// sequentially. LDS = 80KB (w3) + 34KB (tbuf) -> 1 block(8 waves)/CU.
__global__ __launch_bounds__(512, 2) void k_mixm2(
    const float* __restrict__ w3,
    const unsigned int* __restrict__ h2u,    // h2 rows: 32 dwords (64 f16)
    const int* __restrict__ epos,
    unsigned int* __restrict__ mixcsr, int E)
{
    __shared__ unsigned int ws3[640 * 32];   // 81920 B
    __shared__ unsigned int tbuf[8 * 1088];  // 34816 B (per wave: 16 rows x 68)

    for (int idx = threadIdx.x; idx < 640 * 32; idx += 512) {
        int n = idx >> 5, dw = idx & 31;
        int q = dw >> 2, j = dw & 3;
        int kb = q * 8 + 2 * j;
        unsigned int val = packh2(w3[kb * 640 + n], w3[(kb + 1) * 640 + n]);
        ws3[(n << 5) + (((q ^ (n & 7)) << 2) + j)] = val;
    }
    __syncthreads();

    const int lane = threadIdx.x & 63;
    const int wid  = threadIdx.x >> 6;
    const int quad = lane >> 4, nl = lane & 15;
    unsigned int* tb = tbuf + wid * 1088;
    const float sc = 0.125f * INV_SQRT10;
    int ngroups = (E + 15) >> 4;

    for (int g = blockIdx.x * 8 + wid; g < ngroups; g += gridDim.x * 8) {
        int eb = g << 4;
        int erow = eb + nl; if (erow >= E) erow = E - 1;
        const uint4* ha = (const uint4*)(h2u + (size_t)erow * 32);
        f16x8 a0 = __builtin_bit_cast(f16x8, ha[quad]);        // k = quad*8 .. +7
        f16x8 a1 = __builtin_bit_cast(f16x8, ha[quad + 4]);    // k = 32 + quad*8 .. +7
        int posv = epos[erow];   // lane nl holds CSR slot of edge eb+nl

        #pragma unroll
        for (int mm = 0; mm < 5; mm++) {
            f32x4 acc[8];
            #pragma unroll
            for (int t = 0; t < 8; t++) acc[t] = (f32x4){0.f, 0.f, 0.f, 0.f};

            #pragma unroll
            for (int t = 0; t < 8; t++) {
                int nn = (mm * 8 + t) * 16 + nl;               // output column
                const unsigned int* bp = ws3 + (nn << 5);
                int sw = nn & 7;
                f16x8 b0 = __builtin_bit_cast(f16x8, *(const uint4*)(bp + ((quad ^ sw) << 2)));
                f16x8 b1 = __builtin_bit_cast(f16x8, *(const uint4*)(bp + (((quad + 4) ^ sw) << 2)));
                acc[t] = __builtin_amdgcn_mfma_f32_16x16x32_f16(a0, b0, acc[t], 0, 0, 0);
                acc[t] = __builtin_amdgcn_mfma_f32_16x16x32_f16(a1, b1, acc[t], 0, 0, 0);
            }

            float s = (mm == 4) ? sc * SQRT3 : sc;
            // transpose through per-wave LDS (wave-synchronous; all-uint so the
            // compiler tracks the write->read dependency — round-5 lesson)
            #pragma unroll
            for (int tp = 0; tp < 4; tp++)
                #pragma unroll
                for (int r = 0; r < 4; r++)
                    tb[(quad * 4 + r) * 68 + tp * 16 + nl] =
                        packh2(acc[tp][r] * s, acc[tp + 4][r] * s);
            #pragma unroll
            for (int e = 0; e < 16; e++) {
                if (eb + e < E) {
                    int pe = __builtin_amdgcn_readlane(posv, e);
                    mixcsr[(size_t)pe * 320 + mm * 64 + lane] = tb[e * 68 + lane];
                }
            }
        }
    }
}

// ---------------- streaming gather: sequential mix/esrec, only nf gathered ----
__global__ __launch_bounds__(256, 4) void k_gather2(
    const float* __restrict__ node_feats,
    const int*   __restrict__ offsets,
    const float4* __restrict__ esrec,
    const unsigned int* __restrict__ mixcsr,
    float* __restrict__ out, int N)
{
    const int lane = threadIdx.x & 63;
    int node = blockIdx.x * 4 + (threadIdx.x >> 6);
    if (node >= N) return;

    int beg = offsets[node];
    int end = offsets[node + 1];

    float aS[2]     = {0.f, 0.f};
    float aT0[2]    = {0.f, 0.f};
    float aV0[2][3] = {{0.f,0.f,0.f},{0.f,0.f,0.f}};
    float aV1[2][3] = {{0.f,0.f,0.f},{0.f,0.f,0.f}};
    float aV2[2][3] = {{0.f,0.f,0.f},{0.f,0.f,0.f}};

    for (int i = beg; i < end; i += 2) {
        int cnt = end - i; if (cnt > 2) cnt = 2;

        float4 er[2];
        const float* nfp[2];
        unsigned int u[2][5];
        #pragma unroll
        for (int q = 0; q < 2; q++) {
            int ii = (q < cnt) ? i + q : i;
            er[q] = esrec[ii];
            nfp[q] = node_feats + (size_t)__float_as_int(er[q].x) * NF;
            const unsigned int* mp = mixcsr + (size_t)ii * 320 + lane;
            #pragma unroll
            for (int m = 0; m < 5; m++) u[q][m] = mp[m * 64];
        }

        #pragma unroll
        for (int q = 0; q < 2; q++) {
            if (q < cnt) {
                float vx = er[q].y, vy = er[q].z, vz = er[q].w;
                float inv = rsqrtf(vx * vx + vy * vy + vz * vz);
                float rx = vx * inv, ry = vy * inv, rz = vz * inv;
                const float* nf = nfp[q];
                #pragma unroll
                for (int t = 0; t < 2; t++) {
                    int c = lane + 64 * t;
                    float ssv = nf[c];
                    float3 vv = *(const float3*)(nf + CCH + 3 * c);
                    float v0 = vv.x, v1 = vv.y, v2 = vv.z;
                    float d = rx * v0 + ry * v1 + rz * v2;

                    float m0 = t ? h2hi(u[q][0]) : h2lo(u[q][0]);
                    float m1 = t ? h2hi(u[q][1]) : h2lo(u[q][1]);
                    float m2 = t ? h2hi(u[q][2]) : h2lo(u[q][2]);
                    float m3 = t ? h2hi(u[q][3]) : h2lo(u[q][3]);
                    float m4 = t ? h2hi(u[q][4]) : h2lo(u[q][4]);

                    aS[t]  += ssv * m0;
                    aT0[t] += d * m1;
                    aV0[t][0] += v0 * m2;
                    aV0[t][1] += v1 * m2;
                    aV0[t][2] += v2 * m2;
                    aV1[t][0] += ssv * rx * m3;
                    aV1[t][1] += ssv * ry * m3;
                    aV1[t][2] += ssv * rz * m3;
                    aV2[t][0] += (d * rx - v0 * (1.f / 3.f)) * m4;
                    aV2[t][1] += (d * ry - v1 * (1.f / 3.f)) * m4;
                    aV2[t][2] += (d * rz - v2 * (1.f / 3.f)) * m4;
                }
            }
        }
    }

    float* ob = out + (size_t)node * OUTF;
    #pragma unroll
    for (int t = 0; t < 2; t++) {
        int c = lane + 64 * t;
        ob[c]                = aS[t];
        ob[CCH + c]          = aT0[t];
        ob[256  + 3 * c + 0] = aV0[t][0];
        ob[256  + 3 * c + 1] = aV0[t][1];
        ob[256  + 3 * c + 2] = aV0[t][2];
        ob[640  + 3 * c + 0] = aV1[t][0];
        ob[640  + 3 * c + 1] = aV1[t][1];
        ob[640  + 3 * c + 2] = aV1[t][2];
        ob[1024 + 3 * c + 0] = aV2[t][0];
        ob[1024 + 3 * c + 1] = aV2[t][1];
        ob[1024 + 3 * c + 2] = aV2[t][2];
    }
}

// ---------------- fallback fused gather (small-ws path only) ----------------
__global__ __launch_bounds__(512, 4) void k_main_fused(
    const float* __restrict__ vectors,
    const float* __restrict__ node_feats,
    const float* __restrict__ w3,
    const int*   __restrict__ senders,
    const int*   __restrict__ offsets,
    const int*   __restrict__ perm,
    const unsigned int* __restrict__ h2g,
    int* __restrict__ ctr,
    float* __restrict__ out, int N)
{
    __shared__ uint4 wA[32 * 64];
    __shared__ uint4 wB[32 * 64];
    __shared__ uint2 wC[32 * 64];

    for (int idx = threadIdx.x; idx < 32 * 64; idx += 512) {
        int lane = idx & 63, kp = idx >> 6;
        const float* r0 = w3 + (2 * kp) * 640;
        const float* r1 = r0 + 640;
        uint4 A, B; uint2 Cc;
        A.x = packh2(r0[lane],       r1[lane]);
        A.y = packh2(r0[lane + 64],  r1[lane + 64]);
        A.z = packh2(r0[lane + 128], r1[lane + 128]);
        A.w = packh2(r0[lane + 192], r1[lane + 192]);
        B.x = packh2(r0[lane + 256], r1[lane + 256]);
        B.y = packh2(r0[lane + 320], r1[lane + 320]);
        B.z = packh2(r0[lane + 384], r1[lane + 384]);
        B.w = packh2(r0[lane + 448], r1[lane + 448]);
        Cc.x = packh2(r0[lane + 512], r1[lane + 512]);
        Cc.y = packh2(r0[lane + 576], r1[lane + 576]);
        wA[idx] = A; wB[idx] = B; wC[idx] = Cc;
    }
    __syncthreads();

    const int lane = threadIdx.x & 63;

    while (true) {
        int t0 = 0;
        if (lane == 0) t0 = atomicAdd(ctr, 1);
        int node = __shfl(t0, 0, 64);
        if (node >= N) break;
        node = __builtin_amdgcn_readfirstlane(node);

        int beg = offsets[node];
        int end = offsets[node + 1];

        float aS[2]     = {0.f, 0.f};
        float aT0[2]    = {0.f, 0.f};
        float aV0[2][3] = {{0.f,0.f,0.f},{0.f,0.f,0.f}};
        float aV1[2][3] = {{0.f,0.f,0.f},{0.f,0.f,0.f}};
        float aV2[2][3] = {{0.f,0.f,0.f},{0.f,0.f,0.f}};

        for (int i0 = beg; i0 < end; i0 += 4) {
            int rem = end - i0;
            int nq = rem < 4 ? rem : 4;

            const unsigned int* hrow[4];
            float rnx[4], rny[4], rnz[4];
            int   snd[4];

            #pragma unroll
            for (int q = 0; q < 4; q++) {
                int e = (q < nq) ? perm[i0 + q] : perm[i0];
                e = __builtin_amdgcn_readfirstlane(e);
                hrow[q] = h2g + (size_t)e * 32;
                if (q < nq) {
                    float vx = vectors[(size_t)e * 3 + 0];
                    float vy = vectors[(size_t)e * 3 + 1];
                    float vz = vectors[(size_t)e * 3 + 2];
                    float inv = rsqrtf(vx * vx + vy * vy + vz * vz);
                    rnx[q] = vx * inv; rny[q] = vy * inv; rnz[q] = vz * inv;
                    snd[q] = senders[e];
                }
            }

            float mixv[4][10];
            #pragma unroll
            for (int q = 0; q < 4; q++)
                #pragma unroll
                for (int m = 0; m < 10; m++) mixv[q][m] = 0.f;

            #pragma unroll 4
            for (int kp = 0; kp < 32; kp++) {
                unsigned int hq[4];
                #pragma unroll
                for (int q = 0; q < 4; q++) hq[q] = hrow[q][kp];
                uint4 A  = wA[kp * 64 + lane];
                uint4 B  = wB[kp * 64 + lane];
                uint2 Cc = wC[kp * 64 + lane];
                #pragma unroll
                for (int q = 0; q < 4; q++) {
                    unsigned int h = hq[q];
                    mixv[q][0] = dot2(h, A.x,  mixv[q][0]);
                    mixv[q][1] = dot2(h, A.y,  mixv[q][1]);
                    mixv[q][2] = dot2(h, A.z,  mixv[q][2]);
                    mixv[q][3] = dot2(h, A.w,  mixv[q][3]);
                    mixv[q][4] = dot2(h, B.x,  mixv[q][4]);
                    mixv[q][5] = dot2(h, B.y,  mixv[q][5]);
                    mixv[q][6] = dot2(h, B.z,  mixv[q][6]);
                    mixv[q][7] = dot2(h, B.w,  mixv[q][7]);
                    mixv[q][8] = dot2(h, Cc.x, mixv[q][8]);
                    mixv[q][9] = dot2(h, Cc.y, mixv[q][9]);
                }
            }

            const float sc = 0.125f * INV_SQRT10;
            #pragma unroll
            for (int q = 0; q < 4; q++) {
                if (q < nq) {
                    const float* nf = node_feats + (size_t)snd[q] * NF;
                    #pragma unroll
                    for (int t = 0; t < 2; t++) {
                        int c = lane + 64 * t;
                        float ssv = nf[c];
                        float v0 = nf[CCH + 3 * c + 0];
                        float v1 = nf[CCH + 3 * c + 1];
                        float v2 = nf[CCH + 3 * c + 2];
                        float d = rnx[q] * v0 + rny[q] * v1 + rnz[q] * v2;

                        float m0 = mixv[q][t]     * sc;
                        float m1 = mixv[q][2 + t] * sc;
                        float m2 = mixv[q][4 + t] * sc;
                        float m3 = mixv[q][6 + t] * sc;
                        float m4 = mixv[q][8 + t] * sc * SQRT3;

                        aS[t]  += ssv * m0;
                        aT0[t] += d * m1;
                        aV0[t][0] += v0 * m2;
                        aV0[t][1] += v1 * m2;
                        aV0[t][2] += v2 * m2;
                        aV1[t][0] += ssv * rnx[q] * m3;
                        aV1[t][1] += ssv * rny[q] * m3;
                        aV1[t][2] += ssv * rnz[q] * m3;
                        aV2[t][0] += (d * rnx[q] - v0 * (1.f / 3.f)) * m4;
                        aV2[t][1] += (d * rny[q] - v1 * (1.f / 3.f)) * m4;
                        aV2[t][2] += (d * rnz[q] - v2 * (1.f / 3.f)) * m4;
                    }
                }
            }
        }

        float* ob = out + (size_t)node * OUTF;
        #pragma unroll
        for (int t = 0; t < 2; t++) {
            int c = lane + 64 * t;
            ob[c]                = aS[t];
            ob[CCH + c]          = aT0[t];
            ob[256  + 3 * c + 0] = aV0[t][0];
            ob[256  + 3 * c + 1] = aV0[t][1];
            ob[256  + 3 * c + 2] = aV0[t][2];
            ob[640  + 3 * c + 0] = aV1[t][0];
            ob[640  + 3 * c + 1] = aV1[t][1];
            ob[640  + 3 * c + 2] = aV1[t][2];
            ob[1024 + 3 * c + 0] = aV2[t][0];
            ob[1024 + 3 * c + 1] = aV2[t][1];
            ob[1024 + 3 * c + 2] = aV2[t][2];
        }
    }
}

extern "C" void kernel_launch(void* const* d_in, const int* in_sizes, int n_in,
                              void* d_out, int out_size, void* d_ws, size_t ws_size,
                              hipStream_t stream) {
    const float* vectors    = (const float*)d_in[0];
    const float* node_feats = (const float*)d_in[1];
    const float* radial     = (const float*)d_in[2];
    const float* w0         = (const float*)d_in[3];
    const float* w1         = (const float*)d_in[4];
    const float* w2         = (const float*)d_in[5];
    const float* w3         = (const float*)d_in[6];
    const int*   senders    = (const int*)d_in[7];
    const int*   receivers  = (const int*)d_in[8];

    int E = in_sizes[0] / 3;
    int N = in_sizes[1] / NF;

    // ws layout (dwords): mixcsr[E*320] | h2[E*32] | esrec[E*4] | epos[E] |
    //                     perm[E] | counts[N] | ctr[1] | offsets[N+1] | cursor[N]
    size_t small_elems = (size_t)E * 38 + (size_t)3 * N + 2;
    size_t full_elems  = (size_t)E * 320 + small_elems;
    bool big = ws_size >= full_elems * 4;

    unsigned int* mixcsr = (unsigned int*)d_ws;
    unsigned int* h2u  = mixcsr + (big ? (size_t)E * 320 : 0);
    float4* esrec = (float4*)(h2u + (size_t)E * 32);
    int* epos    = (int*)(esrec + E);
    int* perm    = epos + E;
    int* counts  = perm + E;
    int* ctr     = counts + N;
    int* offsets = ctr + 1;
    int* cursor  = offsets + N + 1;
    _Float16* h2f = (_Float16*)h2u;

    k_zero<<<(N + 1 + 255) / 256, 256, 0, stream>>>(counts, N + 1);
    k_hist<<<(E + 255) / 256, 256, 0, stream>>>(receivers, counts, E);
    k_scan<<<1, 1024, 0, stream>>>(counts, offsets, cursor, N);
    k_perm2<<<(E + 255) / 256, 256, 0, stream>>>(receivers, senders, vectors,
                                                 cursor, perm, epos, esrec, E);
    k_mlp2<<<1024, 256, 0, stream>>>(radial, w0, w1, w2, h2f, E);

    if (big) {
        k_mixm2<<<256, 512, 0, stream>>>(w3, h2u, epos, mixcsr, E);
        k_gather2<<<(N + 3) / 4, 256, 0, stream>>>(node_feats, offsets, esrec,
                                                   mixcsr, (float*)d_out, N);
    } else {
        k_main_fused<<<512, 512, 0, stream>>>(vectors, node_feats, w3, senders,
                                              offsets, perm, h2u, ctr,
                                              (float*)d_out, N);
    }
}